// Round 1
// baseline (21440.770 us; speedup 1.0000x reference)
//
#include <hip/hip_runtime.h>
#include <cstddef>

#define T_STEPS 512
#define BATCH   64
#define EDIM    512
#define HDIM    512
#define ODIM    512

// ---------------------------------------------------------------------------
// Parallel GEMM: C[r, n] = sum_k X[r*ldx + k] * W[n*ldw + kw0 + k] + bias[n]
// 64x64x64 tiles, 256 threads, 4x4 micro-tile per thread. M,N,K all % 64 == 0.
// ---------------------------------------------------------------------------
__global__ __launch_bounds__(256) void gemm_bias_kernel(
    const float* __restrict__ X, int ldx,
    const float* __restrict__ W, int ldw, int kw0,
    const float* __restrict__ bias,
    float* __restrict__ C, int ldc, int K)
{
  __shared__ float Xs[64][65];
  __shared__ float Ws[64][65];
  const int tid  = threadIdx.x;
  const int row0 = blockIdx.x * 64;
  const int col0 = blockIdx.y * 64;
  const int tx = tid & 15, ty = tid >> 4;
  float acc[4][4] = {};

  for (int k0 = 0; k0 < K; k0 += 64) {
#pragma unroll
    for (int i = 0; i < 16; ++i) {        // 4096 elems / 256 threads
      int idx = tid + i * 256;
      int r = idx >> 6, c = idx & 63;
      Xs[r][c] = X[(size_t)(row0 + r) * ldx + k0 + c];
      Ws[r][c] = W[(size_t)(col0 + r) * ldw + kw0 + k0 + c];
    }
    __syncthreads();
#pragma unroll
    for (int kk = 0; kk < 64; ++kk) {
      float a[4], b[4];
#pragma unroll
      for (int i = 0; i < 4; ++i) a[i] = Xs[ty * 4 + i][kk];
#pragma unroll
      for (int j = 0; j < 4; ++j) b[j] = Ws[tx * 4 + j][kk];
#pragma unroll
      for (int i = 0; i < 4; ++i)
#pragma unroll
        for (int j = 0; j < 4; ++j) acc[i][j] += a[i] * b[j];
    }
    __syncthreads();
  }

#pragma unroll
  for (int i = 0; i < 4; ++i) {
    size_t r = (size_t)(row0 + ty * 4 + i);
#pragma unroll
    for (int j = 0; j < 4; ++j) {
      int n = col0 + tx * 4 + j;
      C[r * ldc + n] = acc[i][j] + bias[n];
    }
  }
}

// ---------------------------------------------------------------------------
// One recurrence step: h_t = relu(A_t + h_{t-1} @ W1h^T)
//   A, Hbuf: [B*T, H] with row index (b*T + t).
//   grid.x = HDIM/32 = 16 blocks; each block: all 64 batch rows x 32 cols.
// ---------------------------------------------------------------------------
__global__ __launch_bounds__(256) void step_kernel(
    const float* __restrict__ A,
    const float* __restrict__ W1,
    float* __restrict__ Hbuf,
    int t)
{
  __shared__ float Hs[BATCH][65];
  __shared__ float Ws[32][65];
  const int tid  = threadIdx.x;
  const int col0 = blockIdx.x * 32;
  const int tx = tid & 15, ty = tid >> 4;
  float acc[4][2] = {};

  for (int k0 = 0; k0 < HDIM; k0 += 64) {
#pragma unroll
    for (int i = 0; i < 16; ++i) {        // 64x64 h tile
      int idx = tid + i * 256;
      int r = idx >> 6, c = idx & 63;
      Hs[r][c] = (t == 0) ? 0.0f
               : Hbuf[((size_t)r * T_STEPS + (t - 1)) * HDIM + k0 + c];
    }
#pragma unroll
    for (int i = 0; i < 8; ++i) {         // 32x64 W1h tile
      int idx = tid + i * 256;
      int n = idx >> 6, c = idx & 63;
      Ws[n][c] = W1[(size_t)(col0 + n) * (EDIM + HDIM) + EDIM + k0 + c];
    }
    __syncthreads();
#pragma unroll
    for (int kk = 0; kk < 64; ++kk) {
      float a[4], b0, b1;
#pragma unroll
      for (int i = 0; i < 4; ++i) a[i] = Hs[ty * 4 + i][kk];
      b0 = Ws[tx * 2 + 0][kk];
      b1 = Ws[tx * 2 + 1][kk];
#pragma unroll
      for (int i = 0; i < 4; ++i) {
        acc[i][0] += a[i] * b0;
        acc[i][1] += a[i] * b1;
      }
    }
    __syncthreads();
  }

#pragma unroll
  for (int i = 0; i < 4; ++i) {
    int b = ty * 4 + i;
    size_t row = (size_t)b * T_STEPS + t;
#pragma unroll
    for (int j = 0; j < 2; ++j) {
      int n = col0 + tx * 2 + j;
      float v = acc[i][j] + A[row * HDIM + n];
      Hbuf[row * HDIM + n] = v > 0.0f ? v : 0.0f;
    }
  }
}

// ---------------------------------------------------------------------------
// h_final = Hbuf[:, T-1, :]  ->  d_out tail
// ---------------------------------------------------------------------------
__global__ __launch_bounds__(256) void copy_hfinal_kernel(
    const float* __restrict__ Hbuf, float* __restrict__ out)
{
  int i = blockIdx.x * blockDim.x + threadIdx.x;   // 0 .. B*H-1
  int b = i / HDIM, n = i % HDIM;
  out[i] = Hbuf[((size_t)b * T_STEPS + (T_STEPS - 1)) * HDIM + n];
}

extern "C" void kernel_launch(void* const* d_in, const int* in_sizes, int n_in,
                              void* d_out, int out_size, void* d_ws, size_t ws_size,
                              hipStream_t stream) {
  const float* x  = (const float*)d_in[0];   // [B, T, E]
  const float* W1 = (const float*)d_in[1];   // [H, E+H]
  const float* b1 = (const float*)d_in[2];   // [H]
  const float* W2 = (const float*)d_in[3];   // [O, H]
  const float* b2 = (const float*)d_in[4];   // [O]

  float* out  = (float*)d_out;
  // Stage A = X @ W1x^T + b1 in d_out (B*T*H = 16,777,216 <= out_size);
  // it is fully consumed by the step kernels before the final GEMM
  // overwrites d_out with outs.
  float* A    = out;
  float* Hbuf = (float*)d_ws;                // [B*T, H] fp32 = 64 MB

  // 1) A = X @ W1[:, :E]^T + b1
  {
    dim3 grid(BATCH * T_STEPS / 64, HDIM / 64);
    gemm_bias_kernel<<<grid, 256, 0, stream>>>(
        x, EDIM, W1, EDIM + HDIM, /*kw0=*/0, b1, A, HDIM, EDIM);
  }

  // 2) sequential scan: h_t = relu(A_t + h_{t-1} @ W1[:, E:]^T)
  for (int t = 0; t < T_STEPS; ++t) {
    step_kernel<<<HDIM / 32, 256, 0, stream>>>(A, W1, Hbuf, t);
  }

  // 3) outs = Hbuf @ W2^T + b2  (overwrites the A staging area)
  {
    dim3 grid(BATCH * T_STEPS / 64, ODIM / 64);
    gemm_bias_kernel<<<grid, 256, 0, stream>>>(
        Hbuf, HDIM, W2, HDIM, /*kw0=*/0, b2, out, ODIM, HDIM);
  }

  // 4) h_final tail
  copy_hfinal_kernel<<<(BATCH * HDIM) / 256, 256, 0, stream>>>(
      Hbuf, out + (size_t)BATCH * T_STEPS * ODIM);
}

// Round 2
// 3141.608 us; speedup vs baseline: 6.8248x; 6.8248x over previous
//
#include <hip/hip_runtime.h>
#include <cstddef>

#define T_STEPS 512
#define BATCH   64
#define EDIM    512
#define HDIM    512
#define ODIM    512

#define CLUSTERS 4   // batch groups of 16 rows
#define JBLK     8   // blocks per cluster, 64 cols each

typedef __bf16 bf16;
typedef __bf16 bf16x8 __attribute__((ext_vector_type(8)));
typedef float  f32x4  __attribute__((ext_vector_type(4)));

// ---------------------------------------------------------------------------
// Parallel GEMM: C[r,n] = sum_k X[r*ldx+k] * W[n*ldw+kw0+k] + bias[n]
// 64x64x64 tiles, 256 threads, 4x4 micro-tile. XT = float or __bf16.
// ---------------------------------------------------------------------------
template <typename XT>
__global__ __launch_bounds__(256) void gemm_bias_kernel(
    const XT* __restrict__ X, int ldx,
    const float* __restrict__ W, int ldw, int kw0,
    const float* __restrict__ bias,
    float* __restrict__ C, int ldc, int K)
{
  __shared__ float Xs[64][65];
  __shared__ float Ws[64][65];
  const int tid  = threadIdx.x;
  const int row0 = blockIdx.x * 64;
  const int col0 = blockIdx.y * 64;
  const int tx = tid & 15, ty = tid >> 4;
  float acc[4][4] = {};

  for (int k0 = 0; k0 < K; k0 += 64) {
#pragma unroll
    for (int i = 0; i < 16; ++i) {
      int idx = tid + i * 256;
      int r = idx >> 6, c = idx & 63;
      Xs[r][c] = (float)X[(size_t)(row0 + r) * ldx + k0 + c];
      Ws[r][c] = W[(size_t)(col0 + r) * ldw + kw0 + k0 + c];
    }
    __syncthreads();
#pragma unroll
    for (int kk = 0; kk < 64; ++kk) {
      float a[4], b[4];
#pragma unroll
      for (int i = 0; i < 4; ++i) a[i] = Xs[ty * 4 + i][kk];
#pragma unroll
      for (int j = 0; j < 4; ++j) b[j] = Ws[tx * 4 + j][kk];
#pragma unroll
      for (int i = 0; i < 4; ++i)
#pragma unroll
        for (int j = 0; j < 4; ++j) acc[i][j] += a[i] * b[j];
    }
    __syncthreads();
  }

#pragma unroll
  for (int i = 0; i < 4; ++i) {
    size_t r = (size_t)(row0 + ty * 4 + i);
#pragma unroll
    for (int j = 0; j < 4; ++j) {
      int n = col0 + tx * 4 + j;
      C[r * ldc + n] = acc[i][j] + bias[n];
    }
  }
}

// ---------------------------------------------------------------------------
// Persistent scan kernel. Grid = 32 blocks = 4 clusters x 8 blocks.
// Cluster c: batch rows 16c..16c+15. Block j of cluster: cols 64j..64j+63.
// W1h slice lives in LDS as bf16, pre-swizzled into MFMA B-fragment order:
//   entry (nt, kt, lane) = 16B = W1h[col0+16*nt+(lane&15)][32*kt+(lane>>4)*8 .. +7]
// Per step t: acc(16x16 per wave) init from A, 16 MFMAs over K=512 (t>0),
// relu, store h_t bf16, one-phase monotone barrier on cluster counter.
// ---------------------------------------------------------------------------
__global__ __launch_bounds__(256) void scan_kernel(
    const float* __restrict__ A,     // [B*T, H], row = b*T + t (fp32)
    const float* __restrict__ W1,    // [H, E+H] fp32
    bf16* __restrict__ Hbf,          // [B*T, H] bf16, row = b*T + t
    int* __restrict__ ctr)           // CLUSTERS counters, 64-int stride
{
  __shared__ __align__(16) bf16 Wf[4 * 16 * 64 * 8];   // 64 KB

  const int tid  = threadIdx.x;
  const int bid  = blockIdx.x;
  const int c    = bid >> 3;          // cluster
  const int j    = bid & 7;           // block within cluster
  const int col0 = j * 64;
  const int rb0  = c * 16;            // first batch row of cluster

  // ---- one-time: convert + swizzle W1h slice into LDS --------------------
  for (int idx = tid; idx < 4 * 16 * 64; idx += 256) {
    int lane = idx & 63;
    int kt   = (idx >> 6) & 15;
    int nt   = idx >> 10;
    int n    = col0 + nt * 16 + (lane & 15);
    int k    = kt * 32 + (lane >> 4) * 8;
    const float* src = W1 + (size_t)n * (EDIM + HDIM) + EDIM + k;
    bf16x8 v;
#pragma unroll
    for (int u = 0; u < 8; ++u) v[u] = (bf16)src[u];
    *((bf16x8*)&Wf[(size_t)idx * 8]) = v;
  }
  __syncthreads();

  const int w    = tid >> 6;          // wave id = N-tile within block
  const int lane = tid & 63;
  const int q    = lane >> 4;
  const int nl   = lane & 15;
  const int n    = col0 + w * 16 + nl;
  int* myctr     = ctr + c * 64;

  for (int t = 0; t < T_STEPS; ++t) {
    // ---- barrier: wait until all of cluster wrote h_{t-1} ----------------
    if (t > 0) {
      if (tid == 0) {
        while (__hip_atomic_load(myctr, __ATOMIC_RELAXED,
                                 __HIP_MEMORY_SCOPE_AGENT) < JBLK * t) {}
        __threadfence();   // acquire: invalidate stale L1/L2 lines
      }
      __syncthreads();
    }

    // ---- accumulator init = A tile (x-projection + b1) -------------------
    f32x4 acc;
#pragma unroll
    for (int r = 0; r < 4; ++r)
      acc[r] = A[((size_t)(rb0 + q * 4 + r) * T_STEPS + t) * HDIM + n];

    // ---- h_{t-1} @ W1h^T via MFMA ----------------------------------------
    if (t > 0) {
      const bf16* hrow =
          Hbf + ((size_t)(rb0 + nl) * T_STEPS + (t - 1)) * HDIM;
#pragma unroll
      for (int kt = 0; kt < 16; ++kt) {
        bf16x8 a = *((const bf16x8*)(hrow + kt * 32 + q * 8));
        bf16x8 b = *((const bf16x8*)&Wf[(size_t)((w * 16 + kt) * 64 + lane) * 8]);
        acc = __builtin_amdgcn_mfma_f32_16x16x32_bf16(a, b, acc, 0, 0, 0);
      }
    }

    // ---- relu + store h_t (bf16) -----------------------------------------
#pragma unroll
    for (int r = 0; r < 4; ++r) {
      float v = acc[r] > 0.0f ? acc[r] : 0.0f;
      Hbf[((size_t)(rb0 + q * 4 + r) * T_STEPS + t) * HDIM + n] = (bf16)v;
    }

    // ---- signal: h_t of this block is globally visible -------------------
    __syncthreads();                 // drains each wave's vmcnt to L2
    if (tid == 0) {
      __threadfence();               // release: write back dirty L2 lines
      __hip_atomic_fetch_add(myctr, 1, __ATOMIC_RELEASE,
                             __HIP_MEMORY_SCOPE_AGENT);
    }
  }
}

// ---------------------------------------------------------------------------
// h_final = Hbf[:, T-1, :] -> fp32 tail of d_out
// ---------------------------------------------------------------------------
__global__ __launch_bounds__(256) void copy_hfinal_kernel(
    const bf16* __restrict__ Hbf, float* __restrict__ out)
{
  int i = blockIdx.x * blockDim.x + threadIdx.x;   // 0 .. B*H-1
  int b = i / HDIM, n = i % HDIM;
  out[i] = (float)Hbf[((size_t)b * T_STEPS + (T_STEPS - 1)) * HDIM + n];
}

extern "C" void kernel_launch(void* const* d_in, const int* in_sizes, int n_in,
                              void* d_out, int out_size, void* d_ws, size_t ws_size,
                              hipStream_t stream) {
  const float* x  = (const float*)d_in[0];   // [B, T, E]
  const float* W1 = (const float*)d_in[1];   // [H, E+H]
  const float* b1 = (const float*)d_in[2];   // [H]
  const float* W2 = (const float*)d_in[3];   // [O, H]
  const float* b2 = (const float*)d_in[4];   // [O]

  float* out = (float*)d_out;
  // A (x-projection, fp32 [B*T, H] = 64 MB) staged in d_out; fully consumed
  // by scan_kernel before the output GEMM overwrites d_out.
  float* A = out;

  bf16* Hbf = (bf16*)d_ws;                              // 32 MB
  int*  ctr = (int*)((char*)d_ws + (size_t)BATCH * T_STEPS * HDIM * 2);

  // 0) zero the cluster counters (ws is poisoned 0xAA each launch)
  hipMemsetAsync(ctr, 0, CLUSTERS * 64 * sizeof(int), stream);

  // 1) A = X @ W1[:, :E]^T + b1
  {
    dim3 grid(BATCH * T_STEPS / 64, HDIM / 64);
    gemm_bias_kernel<float><<<grid, 256, 0, stream>>>(
        x, EDIM, W1, EDIM + HDIM, /*kw0=*/0, b1, A, HDIM, EDIM);
  }

  // 2) persistent scan: h_t = relu(A_t + h_{t-1} @ W1[:, E:]^T)
  scan_kernel<<<CLUSTERS * JBLK, 256, 0, stream>>>(A, W1, Hbf, ctr);

  // 3) outs = Hbf @ W2^T + b2 (overwrites the A staging area)
  {
    dim3 grid(BATCH * T_STEPS / 64, ODIM / 64);
    gemm_bias_kernel<bf16><<<grid, 256, 0, stream>>>(
        Hbf, HDIM, W2, HDIM, /*kw0=*/0, b2, out, ODIM, HDIM);
  }

  // 4) h_final tail
  copy_hfinal_kernel<<<(BATCH * HDIM) / 256, 256, 0, stream>>>(
      Hbf, out + (size_t)BATCH * T_STEPS * ODIM);
}